// Round 16
// baseline (211.420 us; speedup 1.0000x reference)
//
#include <hip/hip_runtime.h>

#define NN 100000
#define NE 600000
#define NR 6
#define NB 6
#define NKEY (NN * NR)            // 600000 keys: dst*6 + etype
#define NCHUNK ((NKEY + 1023) / 1024)  // 586

typedef __attribute__((ext_vector_type(8))) short bfrag;       // 8 bf16 (4 VGPRs)
typedef __attribute__((ext_vector_type(8))) unsigned short uvec8;
typedef __attribute__((ext_vector_type(4))) float accvec;

__device__ __forceinline__ float bf2f(unsigned short u) {
  union { unsigned int i; float f; } v;
  v.i = ((unsigned int)u) << 16;
  return v.f;
}
__device__ __forceinline__ unsigned short f2bf(float f) {
  union { float f; unsigned int i; } v;
  v.f = f;
  return (unsigned short)((v.i + 0x7FFFu + ((v.i >> 16) & 1u)) >> 16);
}
__device__ __forceinline__ unsigned int cvtpk_bf16(float lo, float hi) {
  unsigned int r;
  asm("v_cvt_pk_bf16_f32 %0, %1, %2" : "=v"(r) : "v"(lo), "v"(hi));
  return r;
}

// ---------- W composition body (fragment layout, stacked-K) ----------
template <int IN, int OUT, int KS, int NT>
__device__ __forceinline__ void compose_body(int idx, const float* __restrict__ V,
                                             const float* __restrict__ C,
                                             const float* __restrict__ S,
                                             unsigned short* __restrict__ Wf) {
  int lane = idx & 63;
  int t = idx >> 6;
  int nt = t % NT; t /= NT;
  int ks = t % KS; int rel = t / KS;
  int n = nt * 16 + (lane & 15);
  int g = lane >> 4;
  uvec8 o;
#pragma unroll
  for (int i = 0; i < 8; ++i) {
    int k = ks * 32 + g * 8 + i;
    float s = 0.f;
    if (k < IN) {
      if (rel < NR) {
#pragma unroll
        for (int b = 0; b < NB; ++b) s += C[rel * NB + b] * V[((size_t)b * IN + k) * OUT + n];
      } else {
        s = S[(size_t)k * OUT + n];
      }
    }
    o[i] = f2bf(s);
  }
  *(uvec8*)&Wf[(size_t)idx * 8] = o;
}

// ---------- fused prep: pad_feats + hist + compose x3 ----------
#define PB_PAD 1563   // ceil(NN*4/256)
#define PB_HIST 2344  // ceil(NE/256)
__global__ __launch_bounds__(256) void prep_kernel(
    const float* __restrict__ nf, unsigned short* __restrict__ hp,
    const int* __restrict__ dst, const int* __restrict__ et, int* __restrict__ cnt,
    const float* V1, const float* C1, const float* S1, unsigned short* W1,
    const float* V2, const float* C2, const float* S2, unsigned short* W2,
    const float* V3, const float* C3, const float* S3, unsigned short* W3) {
  int b = blockIdx.x, tid = threadIdx.x;
  if (b < PB_PAD) {
    int idx = b * 256 + tid;
    if (idx < NN * 4) {
      int n = idx >> 2, c = idx & 3;
      uvec8 o;
#pragma unroll
      for (int i = 0; i < 8; ++i) {
        int k = c * 8 + i;
        o[i] = (k < 26) ? f2bf(nf[n * 26 + k]) : (unsigned short)0;
      }
      *(uvec8*)&hp[(size_t)n * 32 + c * 8] = o;
    }
  } else if (b < PB_PAD + PB_HIST) {
    int e = (b - PB_PAD) * 256 + tid;
    if (e < NE) atomicAdd(&cnt[dst[e] * NR + et[e]], 1);
  } else if (b < PB_PAD + PB_HIST + 7) {
    int idx = (b - PB_PAD - PB_HIST) * 256 + tid;  // 1792 exact
    compose_body<26, 64, 1, 4>(idx, V1, C1, S1, W1);
  } else if (b < PB_PAD + PB_HIST + 7 + 28) {
    int idx = (b - PB_PAD - PB_HIST - 7) * 256 + tid;  // 7168 exact
    compose_body<64, 128, 2, 8>(idx, V2, C2, S2, W2);
  } else {
    int idx = (b - PB_PAD - PB_HIST - 35) * 256 + tid;  // 3584 exact
    compose_body<128, 32, 4, 2>(idx, V3, C3, S3, W3);
  }
}

// ---------- CSR scan ----------
__global__ void scanA(const int* __restrict__ cnt, int* __restrict__ partial) {
  __shared__ int ts[256];
  int t = threadIdx.x;
  int base = blockIdx.x * 1024 + t * 4;
  int s = 0;
#pragma unroll
  for (int i = 0; i < 4; ++i)
    if (base + i < NKEY) s += cnt[base + i];
  ts[t] = s;
  __syncthreads();
  for (int off = 128; off; off >>= 1) {
    if (t < off) ts[t] += ts[t + off];
    __syncthreads();
  }
  if (t == 0) partial[blockIdx.x] = ts[0];
}

// scanC with inline partial prefix. cur aliases cnt.
__global__ void scanC2(int* __restrict__ cnt, const int* __restrict__ partial,
                       int* __restrict__ indptr) {
  __shared__ int ts[256];
  int t = threadIdx.x;
  int bid = blockIdx.x;
  int ps = 0;
  for (int i = t; i < bid; i += 256) ps += partial[i];
  ts[t] = ps;
  __syncthreads();
  for (int off = 128; off; off >>= 1) {
    if (t < off) ts[t] += ts[t + off];
    __syncthreads();
  }
  int base = ts[0];
  __syncthreads();

  int bbase = bid * 1024 + t * 4;
  int v[4], s = 0;
#pragma unroll
  for (int i = 0; i < 4; ++i) {
    v[i] = (bbase + i < NKEY) ? cnt[bbase + i] : 0;
    s += v[i];
  }
  ts[t] = s;
  __syncthreads();
  for (int off = 1; off < 256; off <<= 1) {
    int x = (t >= off) ? ts[t - off] : 0;
    __syncthreads();
    ts[t] += x;
    __syncthreads();
  }
  int run = base + ts[t] - s;
#pragma unroll
  for (int i = 0; i < 4; ++i) {
    if (bbase + i < NKEY) {
      indptr[bbase + i] = run;
      cnt[bbase + i] = run;   // cur
      run += v[i];
    }
  }
  if (bid == 0 && t == 0) indptr[NKEY] = NE;
}

// scatter: erec packs src | rel<<17 (src < 2^17)
__global__ void scatter2(const int* __restrict__ et, const int* __restrict__ src,
                         const int* __restrict__ dst, int* __restrict__ cur,
                         int* __restrict__ erec) {
  int e = blockIdx.x * 256 + threadIdx.x;
  if (e < NE) {
    int r = et[e];
    int s = src[e];
    int key = dst[e] * NR + r;
    int pos = atomicAdd(&cur[key], 1);
    erec[pos] = s | (r << 17);
  }
}

// ---------- fused layer v12: v8 structure, ROWS=8 small blocks for concurrency ----------
// Block = 256 threads, 8 dst rows (half-block: shorter serial chain, 2x more
// independent barrier groups per CU). A-tile declared 16 rows for the MFMA
// read pattern; rows 8-15 are garbage, discarded via write guard (D-row r
// depends only on A-row r, so no contamination).
template <int K, int OUT, int MAXE, bool FUSE3>
__global__ __launch_bounds__(256, 8) void rgcn_layer_v12(
    const unsigned short* __restrict__ h,    // [NN][K] bf16 (pre-relu'd)
    const unsigned short* __restrict__ Wf,   // stacked fragment table (bf16)
    const float* __restrict__ bias,          // [OUT] f32
    const int* __restrict__ indptr,          // [NKEY+1]
    const int* __restrict__ erec,            // [NE] packed src|rel<<17
    unsigned short* __restrict__ Gout,       // [NN][OUT] bf16 (!FUSE3)
    const unsigned short* __restrict__ Wf3,  // W3 fragment table (FUSE3)
    unsigned short* __restrict__ Y3) {       // [(NR+1)*NN][32] (FUSE3)
  constexpr int ROWS = 8;
  constexpr int KS = K / 32;
  constexpr int KT = 7 * KS;
  constexpr int NT = OUT / 16;
  constexpr int NTW = NT / 4;
  constexpr int KC = K / 8;                // 16B chunks per K
  constexpr int LKC = (KC == 4) ? 2 : 3;   // log2(KC)
  constexpr int CT = 7 * KC;               // chunks per row (stacked)
  constexpr int ITEMS = (ROWS * CT + 255) / 256;
  constexpr int KP = 7 * K + 8;            // A-tile row stride (u16)
  constexpr int MSU = K + 8;               // msg row stride (u16)
  constexpr int ATE = 16 * KP;             // declared for 16-row MFMA reads
  constexpr int MGE = MAXE * MSU;
  constexpr int LDSE = ATE > MGE ? ATE : MGE;
  constexpr int SITER = MAXE * KC / 256;

  __shared__ __align__(16) unsigned short A16[LDSE];  // msg buffer, then A tile
  __shared__ int seg[ROWS * NR + 1];

  const int tid = threadIdx.x;
  const int row0 = blockIdx.x * ROWS;

  if (tid < ROWS * NR + 1) seg[tid] = indptr[row0 * NR + tid];
  __syncthreads();

  const int E0 = seg[0];
  const int E1 = seg[ROWS * NR];

  float sum[ITEMS][8];
#pragma unroll
  for (int i = 0; i < ITEMS; ++i)
#pragma unroll
    for (int q = 0; q < 8; ++q) sum[i][q] = 0.f;

  for (int b0 = E0; b0 < E1; b0 += MAXE) {
    const int bcount = min(MAXE, E1 - b0);
    __syncthreads();  // msg free

    // stage: flat gather, tail-clamped (round-12 best-measured variant)
#pragma unroll
    for (int i = 0; i < SITER; ++i) {
      int idx = tid + i * 256;
      int e = idx >> LKC;
      int c = idx & (KC - 1);
      int ec = min(e, bcount - 1);
      int s = erec[b0 + ec] & 0x1FFFF;
      *(uvec8*)&A16[e * MSU + c * 8] = *(const uvec8*)&h[(size_t)s * K + c * 8];
    }
    __syncthreads();

    // accumulate from LDS into per-thread fp32 regs
#pragma unroll
    for (int i = 0; i < ITEMS; ++i) {
      int idx = tid + i * 256;
      if (idx < ROWS * CT) {
        int row = idx / CT, chunk = idx % CT;
        if (chunk < 6 * KC) {
          int rel = chunk >> LKC, c = chunk & (KC - 1);
          int beg = seg[row * NR + rel], end = seg[row * NR + rel + 1];
          int lo = max(beg, b0), hi = min(end, b0 + bcount);
          for (int e = lo; e < hi; ++e) {
            uvec8 t = *(const uvec8*)&A16[(e - b0) * MSU + c * 8];
#pragma unroll
            for (int q = 0; q < 8; ++q) sum[i][q] += bf2f(t[q]);
          }
        }
      }
    }
  }

  __syncthreads();  // msg buffer reusable as A tile

  // pack stacked bf16 A tile (rows 0..ROWS-1 only; upper rows garbage)
#pragma unroll
  for (int i = 0; i < ITEMS; ++i) {
    int idx = tid + i * 256;
    if (idx < ROWS * CT) {
      int row = idx / CT, chunk = idx % CT;
      uint4 w;
      if (chunk >= 6 * KC) {  // self section: direct copy
        int c = chunk - 6 * KC;
        w = *(const uint4*)&h[(size_t)(row0 + row) * K + c * 8];
      } else {
        w.x = cvtpk_bf16(sum[i][0], sum[i][1]);
        w.y = cvtpk_bf16(sum[i][2], sum[i][3]);
        w.z = cvtpk_bf16(sum[i][4], sum[i][5]);
        w.w = cvtpk_bf16(sum[i][6], sum[i][7]);
      }
      *(uint4*)&A16[row * KP + chunk * 8] = w;
    }
  }
  __syncthreads();

  // dense MFMA sweep over stacked K; waves split OUT 4-ways
  const int lane = tid & 63;
  const int wv = tid >> 6;
  const int abase = (lane & 15) * KP + (lane >> 4) * 8;

  accvec acc[NTW];
#pragma unroll
  for (int j = 0; j < NTW; ++j) acc[j] = 0.f;

#pragma unroll
  for (int kst = 0; kst < KT; ++kst) {
    bfrag af = *(const bfrag*)&A16[abase + kst * 32];
#pragma unroll
    for (int j = 0; j < NTW; ++j) {
      int nt = wv * NTW + j;
      bfrag bf = *(const bfrag*)&Wf[(size_t)((kst * NT + nt) * 64 + lane) * 8];
      acc[j] = __builtin_amdgcn_mfma_f32_16x16x32_bf16(af, bf, acc[j], 0, 0, 0);
    }
  }

  // D layout: col=lane&15, row=(lane>>4)*4+reg; rows >= ROWS are garbage
  const int lr0 = (lane >> 4) * 4;
  const int col0 = lane & 15;
  const bool rowok = (lr0 < ROWS);

  if constexpr (!FUSE3) {
    if (rowok) {
#pragma unroll
      for (int j = 0; j < NTW; ++j) {
        int c = (wv * NTW + j) * 16 + col0;
        float bv = bias[c];
#pragma unroll
        for (int r = 0; r < 4; ++r) {
          float v = fmaxf(acc[j][r] + bv, 0.f);
          Gout[(size_t)(row0 + lr0 + r) * OUT + c] = f2bf(v);
        }
      }
    }
  } else {
    // fused layer-3 transform: store relu(acc+b2) tile to LDS, then Y3 = G2t @ W3
    constexpr int GP = 136;  // G2 tile row stride (u16): 2-way bank alias only
    __syncthreads();         // all A16 reads done; overlay G2 tile
#pragma unroll
    for (int j = 0; j < NTW; ++j) {
      int c = (wv * NTW + j) * 16 + col0;
      float bv = bias[c];
#pragma unroll
      for (int r = 0; r < 4; ++r)
        A16[(lr0 + r) * GP + c] = f2bf(fmaxf(acc[j][r] + bv, 0.f));
    }
    __syncthreads();

    const int abase2 = (lane & 15) * GP + (lane >> 4) * 8;
    bfrag a2[4];
#pragma unroll
    for (int ks = 0; ks < 4; ++ks) a2[ks] = *(const bfrag*)&A16[abase2 + ks * 32];

#pragma unroll
    for (int rr = 0; rr < 2; ++rr) {
      int rel = wv + rr * 4;
      if (rel < 7) {
        accvec y[2];
        y[0] = 0.f; y[1] = 0.f;
#pragma unroll
        for (int ks = 0; ks < 4; ++ks) {
#pragma unroll
          for (int nt = 0; nt < 2; ++nt) {
            bfrag bf = *(const bfrag*)&Wf3[(size_t)(((rel * 4 + ks) * 2 + nt) * 64 + lane) * 8];
            y[nt] = __builtin_amdgcn_mfma_f32_16x16x32_bf16(a2[ks], bf, y[nt], 0, 0, 0);
          }
        }
        if (rowok) {
#pragma unroll
          for (int nt = 0; nt < 2; ++nt) {
            int c = nt * 16 + col0;
#pragma unroll
            for (int r = 0; r < 4; ++r)
              Y3[((size_t)rel * NN + row0 + lr0 + r) * 32 + c] = f2bf(y[nt][r]);
          }
        }
      }
    }
  }
}

// ---------- layer 3 phase B: flat segment-sum over all relations ----------
__global__ __launch_bounds__(256, 8) void rgcn_agg3(
    const unsigned short* __restrict__ Y,   // [(NR+1)*NN][32]
    const int* __restrict__ indptr,         // [NKEY+1]
    const int* __restrict__ erec,           // [NE] packed src|rel<<17, sorted by dst
    const float* __restrict__ bias,         // [32]
    float* __restrict__ out) {              // [NN][32] f32
  int t = blockIdx.x * 256 + threadIdx.x;
  int row = t >> 2;
  if (row >= NN) return;
  int c = (t & 3) * 8;

  int beg = indptr[row * NR];
  int end = indptr[row * NR + NR];

  float s[8] = {0.f, 0.f, 0.f, 0.f, 0.f, 0.f, 0.f, 0.f};
  int e = beg;
  for (; e + 3 < end; e += 4) {
    unsigned r0 = erec[e], r1 = erec[e + 1], r2 = erec[e + 2], r3 = erec[e + 3];
    size_t g0 = (size_t)(r0 >> 17) * NN + (r0 & 0x1FFFF);
    size_t g1 = (size_t)(r1 >> 17) * NN + (r1 & 0x1FFFF);
    size_t g2 = (size_t)(r2 >> 17) * NN + (r2 & 0x1FFFF);
    size_t g3 = (size_t)(r3 >> 17) * NN + (r3 & 0x1FFFF);
    uvec8 v0 = *(const uvec8*)&Y[g0 * 32 + c];
    uvec8 v1 = *(const uvec8*)&Y[g1 * 32 + c];
    uvec8 v2 = *(const uvec8*)&Y[g2 * 32 + c];
    uvec8 v3 = *(const uvec8*)&Y[g3 * 32 + c];
#pragma unroll
    for (int i = 0; i < 8; ++i)
      s[i] += (bf2f(v0[i]) + bf2f(v1[i])) + (bf2f(v2[i]) + bf2f(v3[i]));
  }
  for (; e < end; ++e) {
    unsigned r = erec[e];
    size_t g = (size_t)(r >> 17) * NN + (r & 0x1FFFF);
    uvec8 v = *(const uvec8*)&Y[g * 32 + c];
#pragma unroll
    for (int i = 0; i < 8; ++i) s[i] += bf2f(v[i]);
  }
  // self
  uvec8 vs = *(const uvec8*)&Y[((size_t)NR * NN + row) * 32 + c];
#pragma unroll
  for (int i = 0; i < 8; ++i) s[i] += bf2f(vs[i]);

  float4 o0, o1;
  o0.x = fmaxf(s[0] + bias[c + 0], 0.f);
  o0.y = fmaxf(s[1] + bias[c + 1], 0.f);
  o0.z = fmaxf(s[2] + bias[c + 2], 0.f);
  o0.w = fmaxf(s[3] + bias[c + 3], 0.f);
  o1.x = fmaxf(s[4] + bias[c + 4], 0.f);
  o1.y = fmaxf(s[5] + bias[c + 5], 0.f);
  o1.z = fmaxf(s[6] + bias[c + 6], 0.f);
  o1.w = fmaxf(s[7] + bias[c + 7], 0.f);
  *(float4*)&out[(size_t)row * 32 + c] = o0;
  *(float4*)&out[(size_t)row * 32 + c + 4] = o1;
}

// ---------- host ----------
static inline char* align_up(char* p, size_t a) {
  return (char*)(((size_t)p + a - 1) & ~(a - 1));
}

extern "C" void kernel_launch(void* const* d_in, const int* in_sizes, int n_in,
                              void* d_out, int out_size, void* d_ws, size_t ws_size,
                              hipStream_t stream) {
  const float* nf = (const float*)d_in[0];
  const int* src  = (const int*)d_in[1];
  const int* dst  = (const int*)d_in[2];
  const int* et   = (const int*)d_in[3];
  const float* V1 = (const float*)d_in[4];
  const float* C1 = (const float*)d_in[5];
  const float* S1 = (const float*)d_in[6];
  const float* b1 = (const float*)d_in[7];
  const float* V2 = (const float*)d_in[8];
  const float* C2 = (const float*)d_in[9];
  const float* S2 = (const float*)d_in[10];
  const float* b2 = (const float*)d_in[11];
  const float* V3 = (const float*)d_in[12];
  const float* C3 = (const float*)d_in[13];
  const float* S3 = (const float*)d_in[14];
  const float* b3 = (const float*)d_in[15];
  float* out = (float*)d_out;

  // fragment-table element counts (u16): (NR+1)*KS*NT*64*8
  constexpr int WF1 = (NR + 1) * 1 * 4 * 512;  // 14336
  constexpr int WF2 = (NR + 1) * 2 * 8 * 512;  // 57344
  constexpr int WF3 = (NR + 1) * 4 * 2 * 512;  // 28672

  char* p = (char*)d_ws;
  int* cnt = (int*)p;                p = align_up(p + (size_t)NKEY * 4, 256);  // doubles as cur
  int* indptr = (int*)p;             p = align_up(p + (size_t)(NKEY + 1) * 4, 256);
  int* partial = (int*)p;            p = align_up(p + (size_t)NCHUNK * 4, 256);
  int* erec = (int*)p;               p = align_up(p + (size_t)NE * 4, 256);
  unsigned short* hp = (unsigned short*)p;  p = align_up(p + (size_t)NN * 32 * 2, 256);
  unsigned short* W1 = (unsigned short*)p;  p = align_up(p + (size_t)WF1 * 2, 256);
  unsigned short* W2 = (unsigned short*)p;  p = align_up(p + (size_t)WF2 * 2, 256);
  unsigned short* W3 = (unsigned short*)p;  p = align_up(p + (size_t)WF3 * 2, 256);
  unsigned short* G1 = (unsigned short*)p;  p = align_up(p + (size_t)NN * 64 * 2, 256);
  unsigned short* Y3 = (unsigned short*)p;  p = align_up(p + (size_t)(NR + 1) * NN * 32 * 2, 256);

  hipMemsetAsync(cnt, 0, (size_t)NKEY * 4, stream);

  const int EB = (NE + 255) / 256;  // 2344
  prep_kernel<<<PB_PAD + PB_HIST + 49, 256, 0, stream>>>(
      nf, hp, dst, et, cnt, V1, C1, S1, W1, V2, C2, S2, W2, V3, C3, S3, W3);
  scanA<<<NCHUNK, 256, 0, stream>>>(cnt, partial);
  scanC2<<<NCHUNK, 256, 0, stream>>>(cnt, partial, indptr);
  scatter2<<<EB, 256, 0, stream>>>(et, src, dst, cnt, erec);

  const int NB8 = NN / 8;  // 12500 (exact)
  rgcn_layer_v12<32, 64, 64, false><<<NB8, 256, 0, stream>>>(
      hp, W1, b1, indptr, erec, G1, nullptr, nullptr);
  rgcn_layer_v12<64, 128, 64, true><<<NB8, 256, 0, stream>>>(
      G1, W2, b2, indptr, erec, nullptr, W3, Y3);

  rgcn_agg3<<<(NN * 4 + 255) / 256, 256, 0, stream>>>(Y3, indptr, erec, b3, out);

  (void)in_sizes; (void)n_in; (void)out_size; (void)ws_size;
}

// Round 17
// 171.770 us; speedup vs baseline: 1.2308x; 1.2308x over previous
//
#include <hip/hip_runtime.h>

#define NN 100000
#define NE 600000
#define NR 6
#define NB 6
#define NKEY (NN * NR)            // 600000 keys: dst*6 + etype
#define NCHUNK ((NKEY + 1023) / 1024)  // 586

typedef __attribute__((ext_vector_type(8))) short bfrag;       // 8 bf16 (4 VGPRs)
typedef __attribute__((ext_vector_type(8))) unsigned short uvec8;
typedef __attribute__((ext_vector_type(4))) float accvec;

__device__ __forceinline__ float bf2f(unsigned short u) {
  union { unsigned int i; float f; } v;
  v.i = ((unsigned int)u) << 16;
  return v.f;
}
__device__ __forceinline__ unsigned short f2bf(float f) {
  union { float f; unsigned int i; } v;
  v.f = f;
  return (unsigned short)((v.i + 0x7FFFu + ((v.i >> 16) & 1u)) >> 16);
}
__device__ __forceinline__ unsigned int cvtpk_bf16(float lo, float hi) {
  unsigned int r;
  asm("v_cvt_pk_bf16_f32 %0, %1, %2" : "=v"(r) : "v"(lo), "v"(hi));
  return r;
}

// ---------- W composition body (fragment layout, stacked-K) ----------
template <int IN, int OUT, int KS, int NT>
__device__ __forceinline__ void compose_body(int idx, const float* __restrict__ V,
                                             const float* __restrict__ C,
                                             const float* __restrict__ S,
                                             unsigned short* __restrict__ Wf) {
  int lane = idx & 63;
  int t = idx >> 6;
  int nt = t % NT; t /= NT;
  int ks = t % KS; int rel = t / KS;
  int n = nt * 16 + (lane & 15);
  int g = lane >> 4;
  uvec8 o;
#pragma unroll
  for (int i = 0; i < 8; ++i) {
    int k = ks * 32 + g * 8 + i;
    float s = 0.f;
    if (k < IN) {
      if (rel < NR) {
#pragma unroll
        for (int b = 0; b < NB; ++b) s += C[rel * NB + b] * V[((size_t)b * IN + k) * OUT + n];
      } else {
        s = S[(size_t)k * OUT + n];
      }
    }
    o[i] = f2bf(s);
  }
  *(uvec8*)&Wf[(size_t)idx * 8] = o;
}

// ---------- fused prep: pad_feats + hist + compose x3 ----------
#define PB_PAD 1563   // ceil(NN*4/256)
#define PB_HIST 2344  // ceil(NE/256)
__global__ __launch_bounds__(256) void prep_kernel(
    const float* __restrict__ nf, unsigned short* __restrict__ hp,
    const int* __restrict__ dst, const int* __restrict__ et, int* __restrict__ cnt,
    const float* V1, const float* C1, const float* S1, unsigned short* W1,
    const float* V2, const float* C2, const float* S2, unsigned short* W2,
    const float* V3, const float* C3, const float* S3, unsigned short* W3) {
  int b = blockIdx.x, tid = threadIdx.x;
  if (b < PB_PAD) {
    int idx = b * 256 + tid;
    if (idx < NN * 4) {
      int n = idx >> 2, c = idx & 3;
      uvec8 o;
#pragma unroll
      for (int i = 0; i < 8; ++i) {
        int k = c * 8 + i;
        o[i] = (k < 26) ? f2bf(nf[n * 26 + k]) : (unsigned short)0;
      }
      *(uvec8*)&hp[(size_t)n * 32 + c * 8] = o;
    }
  } else if (b < PB_PAD + PB_HIST) {
    int e = (b - PB_PAD) * 256 + tid;
    if (e < NE) atomicAdd(&cnt[dst[e] * NR + et[e]], 1);
  } else if (b < PB_PAD + PB_HIST + 7) {
    int idx = (b - PB_PAD - PB_HIST) * 256 + tid;  // 1792 exact
    compose_body<26, 64, 1, 4>(idx, V1, C1, S1, W1);
  } else if (b < PB_PAD + PB_HIST + 7 + 28) {
    int idx = (b - PB_PAD - PB_HIST - 7) * 256 + tid;  // 7168 exact
    compose_body<64, 128, 2, 8>(idx, V2, C2, S2, W2);
  } else {
    int idx = (b - PB_PAD - PB_HIST - 35) * 256 + tid;  // 3584 exact
    compose_body<128, 32, 4, 2>(idx, V3, C3, S3, W3);
  }
}

// ---------- CSR scan ----------
__global__ void scanA(const int* __restrict__ cnt, int* __restrict__ partial) {
  __shared__ int ts[256];
  int t = threadIdx.x;
  int base = blockIdx.x * 1024 + t * 4;
  int s = 0;
#pragma unroll
  for (int i = 0; i < 4; ++i)
    if (base + i < NKEY) s += cnt[base + i];
  ts[t] = s;
  __syncthreads();
  for (int off = 128; off; off >>= 1) {
    if (t < off) ts[t] += ts[t + off];
    __syncthreads();
  }
  if (t == 0) partial[blockIdx.x] = ts[0];
}

// scanC with inline partial prefix. cur aliases cnt.
__global__ void scanC2(int* __restrict__ cnt, const int* __restrict__ partial,
                       int* __restrict__ indptr) {
  __shared__ int ts[256];
  int t = threadIdx.x;
  int bid = blockIdx.x;
  int ps = 0;
  for (int i = t; i < bid; i += 256) ps += partial[i];
  ts[t] = ps;
  __syncthreads();
  for (int off = 128; off; off >>= 1) {
    if (t < off) ts[t] += ts[t + off];
    __syncthreads();
  }
  int base = ts[0];
  __syncthreads();

  int bbase = bid * 1024 + t * 4;
  int v[4], s = 0;
#pragma unroll
  for (int i = 0; i < 4; ++i) {
    v[i] = (bbase + i < NKEY) ? cnt[bbase + i] : 0;
    s += v[i];
  }
  ts[t] = s;
  __syncthreads();
  for (int off = 1; off < 256; off <<= 1) {
    int x = (t >= off) ? ts[t - off] : 0;
    __syncthreads();
    ts[t] += x;
    __syncthreads();
  }
  int run = base + ts[t] - s;
#pragma unroll
  for (int i = 0; i < 4; ++i) {
    if (bbase + i < NKEY) {
      indptr[bbase + i] = run;
      cnt[bbase + i] = run;   // cur
      run += v[i];
    }
  }
  if (bid == 0 && t == 0) indptr[NKEY] = NE;
}

// scatter: erec packs src | rel<<17 (src < 2^17)
__global__ void scatter2(const int* __restrict__ et, const int* __restrict__ src,
                         const int* __restrict__ dst, int* __restrict__ cur,
                         int* __restrict__ erec) {
  int e = blockIdx.x * 256 + threadIdx.x;
  if (e < NE) {
    int r = et[e];
    int s = src[e];
    int key = dst[e] * NR + r;
    int pos = atomicAdd(&cur[key], 1);
    erec[pos] = s | (r << 17);
  }
}

// ---------- fused layer v8p: round-12 v8 structure + setprio around MFMA ----------
template <int K, int OUT, int MAXE, bool FUSE3>
__global__ __launch_bounds__(256, 8) void rgcn_layer_v8p(
    const unsigned short* __restrict__ h,    // [NN][K] bf16 (pre-relu'd)
    const unsigned short* __restrict__ Wf,   // stacked fragment table (bf16)
    const float* __restrict__ bias,          // [OUT] f32
    const int* __restrict__ indptr,          // [NKEY+1]
    const int* __restrict__ erec,            // [NE] packed src|rel<<17
    unsigned short* __restrict__ Gout,       // [NN][OUT] bf16 (!FUSE3)
    const unsigned short* __restrict__ Wf3,  // W3 fragment table (FUSE3)
    unsigned short* __restrict__ Y3) {       // [(NR+1)*NN][32] (FUSE3)
  constexpr int ROWS = 16;
  constexpr int KS = K / 32;
  constexpr int KT = 7 * KS;
  constexpr int NT = OUT / 16;
  constexpr int NTW = NT / 4;
  constexpr int KC = K / 8;                // 16B chunks per K
  constexpr int LKC = (KC == 4) ? 2 : 3;   // log2(KC)
  constexpr int CT = 7 * KC;               // chunks per row (stacked)
  constexpr int ITEMS = (ROWS * CT + 255) / 256;
  constexpr int KP = 7 * K + 8;            // A-tile row stride (u16)
  constexpr int MSU = K + 8;               // msg row stride (u16)
  constexpr int ATE = ROWS * KP;
  constexpr int MGE = MAXE * MSU;
  constexpr int LDSE = ATE > MGE ? ATE : MGE;
  constexpr int SITER = MAXE * KC / 256;

  __shared__ __align__(16) unsigned short A16[LDSE];  // msg buffer, then A tile
  __shared__ int seg[ROWS * NR + 1];

  const int tid = threadIdx.x;
  const int row0 = blockIdx.x * ROWS;

  if (tid < ROWS * NR + 1) seg[tid] = indptr[row0 * NR + tid];
  __syncthreads();

  const int E0 = seg[0];
  const int E1 = seg[ROWS * NR];

  float sum[ITEMS][8];
#pragma unroll
  for (int i = 0; i < ITEMS; ++i)
#pragma unroll
    for (int q = 0; q < 8; ++q) sum[i][q] = 0.f;

  for (int b0 = E0; b0 < E1; b0 += MAXE) {
    const int bcount = min(MAXE, E1 - b0);
    __syncthreads();  // msg free

    // stage: flat gather, tail-clamped (round-12 best-measured variant)
#pragma unroll
    for (int i = 0; i < SITER; ++i) {
      int idx = tid + i * 256;
      int e = idx >> LKC;
      int c = idx & (KC - 1);
      int ec = min(e, bcount - 1);
      int s = erec[b0 + ec] & 0x1FFFF;
      *(uvec8*)&A16[e * MSU + c * 8] = *(const uvec8*)&h[(size_t)s * K + c * 8];
    }
    __syncthreads();

    // accumulate from LDS into per-thread fp32 regs
#pragma unroll
    for (int i = 0; i < ITEMS; ++i) {
      int idx = tid + i * 256;
      if (idx < ROWS * CT) {
        int row = idx / CT, chunk = idx % CT;
        if (chunk < 6 * KC) {
          int rel = chunk >> LKC, c = chunk & (KC - 1);
          int beg = seg[row * NR + rel], end = seg[row * NR + rel + 1];
          int lo = max(beg, b0), hi = min(end, b0 + bcount);
          for (int e = lo; e < hi; ++e) {
            uvec8 t = *(const uvec8*)&A16[(e - b0) * MSU + c * 8];
#pragma unroll
            for (int q = 0; q < 8; ++q) sum[i][q] += bf2f(t[q]);
          }
        }
      }
    }
  }

  __syncthreads();  // msg buffer reusable as A tile

  // pack stacked bf16 A tile (cvt_pk: 4 insts per 8 elems)
#pragma unroll
  for (int i = 0; i < ITEMS; ++i) {
    int idx = tid + i * 256;
    if (idx < ROWS * CT) {
      int row = idx / CT, chunk = idx % CT;
      uint4 w;
      if (chunk >= 6 * KC) {  // self section: direct copy
        int c = chunk - 6 * KC;
        w = *(const uint4*)&h[(size_t)(row0 + row) * K + c * 8];
      } else {
        w.x = cvtpk_bf16(sum[i][0], sum[i][1]);
        w.y = cvtpk_bf16(sum[i][2], sum[i][3]);
        w.z = cvtpk_bf16(sum[i][4], sum[i][5]);
        w.w = cvtpk_bf16(sum[i][6], sum[i][7]);
      }
      *(uint4*)&A16[row * KP + chunk * 8] = w;
    }
  }
  __syncthreads();

  // dense MFMA sweep over stacked K; waves split OUT 4-ways
  const int lane = tid & 63;
  const int wv = tid >> 6;
  const int abase = (lane & 15) * KP + (lane >> 4) * 8;

  accvec acc[NTW];
#pragma unroll
  for (int j = 0; j < NTW; ++j) acc[j] = 0.f;

  __builtin_amdgcn_s_setprio(1);
#pragma unroll
  for (int kst = 0; kst < KT; ++kst) {
    bfrag af = *(const bfrag*)&A16[abase + kst * 32];
#pragma unroll
    for (int j = 0; j < NTW; ++j) {
      int nt = wv * NTW + j;
      bfrag bf = *(const bfrag*)&Wf[(size_t)((kst * NT + nt) * 64 + lane) * 8];
      acc[j] = __builtin_amdgcn_mfma_f32_16x16x32_bf16(af, bf, acc[j], 0, 0, 0);
    }
  }
  __builtin_amdgcn_s_setprio(0);

  // D layout: col=lane&15, row=(lane>>4)*4+reg
  const int lr0 = (lane >> 4) * 4;
  const int col0 = lane & 15;

  if constexpr (!FUSE3) {
#pragma unroll
    for (int j = 0; j < NTW; ++j) {
      int c = (wv * NTW + j) * 16 + col0;
      float bv = bias[c];
#pragma unroll
      for (int r = 0; r < 4; ++r) {
        float v = fmaxf(acc[j][r] + bv, 0.f);
        Gout[(size_t)(row0 + lr0 + r) * OUT + c] = f2bf(v);
      }
    }
  } else {
    // fused layer-3 transform: store relu(acc+b2) tile to LDS, then Y3 = G2t @ W3
    constexpr int GP = 136;  // G2 tile row stride (u16): 2-way bank alias only
    __syncthreads();         // all A16 reads done; overlay G2 tile
#pragma unroll
    for (int j = 0; j < NTW; ++j) {
      int c = (wv * NTW + j) * 16 + col0;
      float bv = bias[c];
#pragma unroll
      for (int r = 0; r < 4; ++r)
        A16[(lr0 + r) * GP + c] = f2bf(fmaxf(acc[j][r] + bv, 0.f));
    }
    __syncthreads();

    const int abase2 = (lane & 15) * GP + (lane >> 4) * 8;
    bfrag a2[4];
#pragma unroll
    for (int ks = 0; ks < 4; ++ks) a2[ks] = *(const bfrag*)&A16[abase2 + ks * 32];

    __builtin_amdgcn_s_setprio(1);
#pragma unroll
    for (int rr = 0; rr < 2; ++rr) {
      int rel = wv + rr * 4;
      if (rel < 7) {
        accvec y[2];
        y[0] = 0.f; y[1] = 0.f;
#pragma unroll
        for (int ks = 0; ks < 4; ++ks) {
#pragma unroll
          for (int nt = 0; nt < 2; ++nt) {
            bfrag bf = *(const bfrag*)&Wf3[(size_t)(((rel * 4 + ks) * 2 + nt) * 64 + lane) * 8];
            y[nt] = __builtin_amdgcn_mfma_f32_16x16x32_bf16(a2[ks], bf, y[nt], 0, 0, 0);
          }
        }
#pragma unroll
        for (int nt = 0; nt < 2; ++nt) {
          int c = nt * 16 + col0;
#pragma unroll
          for (int r = 0; r < 4; ++r)
            Y3[((size_t)rel * NN + row0 + lr0 + r) * 32 + c] = f2bf(y[nt][r]);
        }
      }
    }
    __builtin_amdgcn_s_setprio(0);
  }
}

// ---------- layer 3 phase B: flat segment-sum over all relations ----------
__global__ __launch_bounds__(256, 8) void rgcn_agg3(
    const unsigned short* __restrict__ Y,   // [(NR+1)*NN][32]
    const int* __restrict__ indptr,         // [NKEY+1]
    const int* __restrict__ erec,           // [NE] packed src|rel<<17, sorted by dst
    const float* __restrict__ bias,         // [32]
    float* __restrict__ out) {              // [NN][32] f32
  int t = blockIdx.x * 256 + threadIdx.x;
  int row = t >> 2;
  if (row >= NN) return;
  int c = (t & 3) * 8;

  int beg = indptr[row * NR];
  int end = indptr[row * NR + NR];

  float s[8] = {0.f, 0.f, 0.f, 0.f, 0.f, 0.f, 0.f, 0.f};
  int e = beg;
  for (; e + 3 < end; e += 4) {
    unsigned r0 = erec[e], r1 = erec[e + 1], r2 = erec[e + 2], r3 = erec[e + 3];
    size_t g0 = (size_t)(r0 >> 17) * NN + (r0 & 0x1FFFF);
    size_t g1 = (size_t)(r1 >> 17) * NN + (r1 & 0x1FFFF);
    size_t g2 = (size_t)(r2 >> 17) * NN + (r2 & 0x1FFFF);
    size_t g3 = (size_t)(r3 >> 17) * NN + (r3 & 0x1FFFF);
    uvec8 v0 = *(const uvec8*)&Y[g0 * 32 + c];
    uvec8 v1 = *(const uvec8*)&Y[g1 * 32 + c];
    uvec8 v2 = *(const uvec8*)&Y[g2 * 32 + c];
    uvec8 v3 = *(const uvec8*)&Y[g3 * 32 + c];
#pragma unroll
    for (int i = 0; i < 8; ++i)
      s[i] += (bf2f(v0[i]) + bf2f(v1[i])) + (bf2f(v2[i]) + bf2f(v3[i]));
  }
  for (; e < end; ++e) {
    unsigned r = erec[e];
    size_t g = (size_t)(r >> 17) * NN + (r & 0x1FFFF);
    uvec8 v = *(const uvec8*)&Y[g * 32 + c];
#pragma unroll
    for (int i = 0; i < 8; ++i) s[i] += bf2f(v[i]);
  }
  // self
  uvec8 vs = *(const uvec8*)&Y[((size_t)NR * NN + row) * 32 + c];
#pragma unroll
  for (int i = 0; i < 8; ++i) s[i] += bf2f(vs[i]);

  float4 o0, o1;
  o0.x = fmaxf(s[0] + bias[c + 0], 0.f);
  o0.y = fmaxf(s[1] + bias[c + 1], 0.f);
  o0.z = fmaxf(s[2] + bias[c + 2], 0.f);
  o0.w = fmaxf(s[3] + bias[c + 3], 0.f);
  o1.x = fmaxf(s[4] + bias[c + 4], 0.f);
  o1.y = fmaxf(s[5] + bias[c + 5], 0.f);
  o1.z = fmaxf(s[6] + bias[c + 6], 0.f);
  o1.w = fmaxf(s[7] + bias[c + 7], 0.f);
  *(float4*)&out[(size_t)row * 32 + c] = o0;
  *(float4*)&out[(size_t)row * 32 + c + 4] = o1;
}

// ---------- host ----------
static inline char* align_up(char* p, size_t a) {
  return (char*)(((size_t)p + a - 1) & ~(a - 1));
}

extern "C" void kernel_launch(void* const* d_in, const int* in_sizes, int n_in,
                              void* d_out, int out_size, void* d_ws, size_t ws_size,
                              hipStream_t stream) {
  const float* nf = (const float*)d_in[0];
  const int* src  = (const int*)d_in[1];
  const int* dst  = (const int*)d_in[2];
  const int* et   = (const int*)d_in[3];
  const float* V1 = (const float*)d_in[4];
  const float* C1 = (const float*)d_in[5];
  const float* S1 = (const float*)d_in[6];
  const float* b1 = (const float*)d_in[7];
  const float* V2 = (const float*)d_in[8];
  const float* C2 = (const float*)d_in[9];
  const float* S2 = (const float*)d_in[10];
  const float* b2 = (const float*)d_in[11];
  const float* V3 = (const float*)d_in[12];
  const float* C3 = (const float*)d_in[13];
  const float* S3 = (const float*)d_in[14];
  const float* b3 = (const float*)d_in[15];
  float* out = (float*)d_out;

  // fragment-table element counts (u16): (NR+1)*KS*NT*64*8
  constexpr int WF1 = (NR + 1) * 1 * 4 * 512;  // 14336
  constexpr int WF2 = (NR + 1) * 2 * 8 * 512;  // 57344
  constexpr int WF3 = (NR + 1) * 4 * 2 * 512;  // 28672

  char* p = (char*)d_ws;
  int* cnt = (int*)p;                p = align_up(p + (size_t)NKEY * 4, 256);  // doubles as cur
  int* indptr = (int*)p;             p = align_up(p + (size_t)(NKEY + 1) * 4, 256);
  int* partial = (int*)p;            p = align_up(p + (size_t)NCHUNK * 4, 256);
  int* erec = (int*)p;               p = align_up(p + (size_t)NE * 4, 256);
  unsigned short* hp = (unsigned short*)p;  p = align_up(p + (size_t)NN * 32 * 2, 256);
  unsigned short* W1 = (unsigned short*)p;  p = align_up(p + (size_t)WF1 * 2, 256);
  unsigned short* W2 = (unsigned short*)p;  p = align_up(p + (size_t)WF2 * 2, 256);
  unsigned short* W3 = (unsigned short*)p;  p = align_up(p + (size_t)WF3 * 2, 256);
  unsigned short* G1 = (unsigned short*)p;  p = align_up(p + (size_t)NN * 64 * 2, 256);
  unsigned short* Y3 = (unsigned short*)p;  p = align_up(p + (size_t)(NR + 1) * NN * 32 * 2, 256);

  hipMemsetAsync(cnt, 0, (size_t)NKEY * 4, stream);

  const int EB = (NE + 255) / 256;  // 2344
  prep_kernel<<<PB_PAD + PB_HIST + 49, 256, 0, stream>>>(
      nf, hp, dst, et, cnt, V1, C1, S1, W1, V2, C2, S2, W2, V3, C3, S3, W3);
  scanA<<<NCHUNK, 256, 0, stream>>>(cnt, partial);
  scanC2<<<NCHUNK, 256, 0, stream>>>(cnt, partial, indptr);
  scatter2<<<EB, 256, 0, stream>>>(et, src, dst, cnt, erec);

  const int NB16 = NN / 16;  // 6250 (exact)
  rgcn_layer_v8p<32, 64, 128, false><<<NB16, 256, 0, stream>>>(
      hp, W1, b1, indptr, erec, G1, nullptr, nullptr);
  rgcn_layer_v8p<64, 128, 128, true><<<NB16, 256, 0, stream>>>(
      G1, W2, b2, indptr, erec, nullptr, W3, Y3);

  rgcn_agg3<<<(NN * 4 + 255) / 256, 256, 0, stream>>>(Y3, indptr, erec, b3, out);

  (void)in_sizes; (void)n_in; (void)out_size; (void)ws_size;
}